// Round 5
// baseline (182.595 us; speedup 1.0000x reference)
//
#include <hip/hip_runtime.h>
#include <hip/hip_fp16.h>

// CIN (xDeepFM), B=4096, F=32, D=64, layers 128/128.
// Per row m=(b,d): t = x[b,:,d] (32 f32)
//   layer0: y0[o] = relu(b0[o] + sum_{h,f} w0[o, h*32+f] t[h] t[f])
//   hidden = y0[0:64]; direct0 = y0[64:128]
//   layer1: y1[o] = relu(b1[o] + sum_{hh,f} w1[o, hh*32+f] hidden[hh] t[f])
//   out[b] = concat(direct0, y1) summed over d  -> (4096, 192) f32
//
// Round-14: R13's 32x32x16 switch regressed (182 vs 162.5) because the
// burst order (nt outer, s middle, mt inner) gave acc[mt][nt] a reuse
// distance of TWO MFMAs -- far below the 32x32 dependent-MFMA latency
// (~30+ cyc) -> per-pair dependency stalls (VALUBusy fell 31->23.5 with
// no util gain). Fix: s-OUTER burst order; each acc is re-read 8 MFMAs
// (~70 cyc) after its write. Everything else identical to R13.
//
// MFMA mapping (v_mfma_f32_32x32x16_f16):
//   A frag: lane holds A[m = l&31][k = (l>>5)*8 + j]   (j = 0..7)
//   B frag: lane holds B[k = (l>>5)*8 + j][n = l&31]
//   C/D   : col = l&31, row = (reg&3) + 8*(reg>>2) + 4*(l>>5), reg 0..15
// Chunk kt = 32 K-rows of Z; per chunk 2 K-steps (s=0,1) of 16.
// A elem j of (mt,s): t[d][f]*th, d = mt*32+(l&31), f = s*16+(l>>5)*8+j.

typedef __attribute__((ext_vector_type(8))) _Float16 f16x8;
typedef __attribute__((ext_vector_type(16))) float f32x16;
typedef __attribute__((ext_vector_type(4))) unsigned short us4;
typedef unsigned short ushortT;

// ---------- weight pre-pack: f32 -> f16 in B-fragment order ----------
// Chunk ktg (8192 B = 4096 ushorts): frag (nt, s) at ushort offset
// ktg*4096 + nt*1024 + s*512 + l*8 (+j).  B[k][n] = w[o = nt*32+(l&31)]
// [c = kt*32 + s*16 + (l>>5)*8 + j].  ktg<32 -> w0; ktg>=32 -> w1.
__global__ void cin_pack_w(const float* __restrict__ w0,
                           const float* __restrict__ w1,
                           ushortT* __restrict__ wp) {
    int gidx = blockIdx.x * 256 + threadIdx.x;
    if (gidx >= 49152) return;
    int ktg = gidx >> 9;
    int rem = gidx & 511;
    int nt  = rem >> 7;
    int s   = (rem >> 6) & 1;
    int l   = rem & 63;
    int o   = nt * 32 + (l & 31);
    int cb  = s * 16 + ((l >> 5) << 3);
    const float* src;
    if (ktg < 32) src = w0 + (size_t)o * 1024 + ktg * 32 + cb;
    else          src = w1 + (size_t)o * 2048 + (ktg - 32) * 32 + cb;
    ushortT* dst = wp + (size_t)gidx * 8;
    ushortT tmp[8];
#pragma unroll
    for (int j = 0; j < 8; ++j) {
        __half h = __float2half(src[j]);
        tmp[j] = __builtin_bit_cast(ushortT, h);
    }
    *reinterpret_cast<f16x8*>(dst) = *reinterpret_cast<const f16x8*>(tmp);
}

__global__ __launch_bounds__(256, 2) void cin_mfma_kernel(
    const float* __restrict__ x,      // [4096][32][64]
    const float* __restrict__ b0,     // [128]
    const float* __restrict__ b1,     // [128]
    const ushortT* __restrict__ wp,   // packed weights (f16 bits)
    float* __restrict__ out)          // [4096][192]
{
    const int tid = threadIdx.x;
    const int l   = tid & 63;         // lane
    const int w   = tid >> 6;         // wave 0..3 -> b = blockIdx*4 + w
    const int b   = blockIdx.x * 4 + w;
    const int l31 = l & 31;
    const int g5  = l >> 5;

    // Union buffer per wave: x table rows 0..31 (stride 64) during layer 0,
    // then hidden rows 0..63 (stride 68, bank-friendly) after the boundary.
    __shared__ ushortT U[4][4352];                    // 34 KB
    __shared__ __align__(16) ushortT Wb[2][8192];     // pair dbuf (32 KB)

    ushortT* Xw = U[w];    // also Hw (stride 68) after the boundary

    // ---- prologue: x (f32) -> f16 table Xw rows 0..31 (own wave) ----
    const float* xb = x + (size_t)b * 2048;
#pragma unroll
    for (int i = 0; i < 8; ++i) {
        float4 v = reinterpret_cast<const float4*>(xb)[i * 64 + l];
        int flat = (i * 64 + l) * 4;
        us4 h;
        h[0] = __builtin_bit_cast(ushortT, __float2half(v.x));
        h[1] = __builtin_bit_cast(ushortT, __float2half(v.y));
        h[2] = __builtin_bit_cast(ushortT, __float2half(v.z));
        h[3] = __builtin_bit_cast(ushortT, __float2half(v.w));
        *reinterpret_cast<us4*>(&Xw[flat]) = h;
    }

    // ---- stage pair 0 (chunks 0,1 = 16 KB) into slot 0: 4 x 1 KB/wave ----
#pragma unroll
    for (int j = 0; j < 4; ++j) {
        const int seg = w * 4 + j;
        const char* src = (const char*)wp + (size_t)seg * 1024 + (size_t)l * 16;
        __builtin_amdgcn_global_load_lds((const unsigned int*)src,
                                         (unsigned int*)&Wb[0][seg * 512], 16, 0, 0);
    }
    __syncthreads();   // drains vmcnt (pair 0) + lgkm (Xw fill)

    // ---- base T-fragments: tf[mt][s][q] = (t[d][f0], t[d][f0+1]),
    //      d = mt*32+l31, f0 = s*16 + g5*8 + 2q ----
    __half2 tf[2][2][4];
#pragma unroll
    for (int mt = 0; mt < 2; ++mt)
#pragma unroll
        for (int s = 0; s < 2; ++s)
#pragma unroll
            for (int q = 0; q < 4; ++q) {
                int f0 = s * 16 + g5 * 8 + 2 * q;
                unsigned lo = Xw[f0 * 64 + mt * 32 + l31];
                unsigned hi = Xw[(f0 + 1) * 64 + mt * 32 + l31];
                tf[mt][s][q] = __builtin_bit_cast(__half2, lo | (hi << 16));
            }

    f32x16 acc[2][4];
#pragma unroll
    for (int mt = 0; mt < 2; ++mt)
#pragma unroll
        for (int nt = 0; nt < 4; ++nt)
#pragma unroll
            for (int r = 0; r < 16; ++r) acc[mt][nt][r] = 0.f;

    union AfU { __half2 h2[4]; f16x8 v; };

    // ---------------- phase loop: 48 phases x 2 chunks ----------------
    // Phase p consumes pair p from slot p&1, stages pair p+1 into the
    // other slot. One barrier per phase (32 MFMAs of 32x32x16 each).
#pragma unroll 1
    for (int p = 0; p < 48; ++p) {
        const int ps = p & 1;
        const int k0 = 2 * p;
        const int k1 = k0 + 1;

        // stage next pair (issued first; lands during this phase body)
        if (p + 1 < 48) {
#pragma unroll
            for (int j = 0; j < 4; ++j) {
                const int seg = w * 4 + j;
                const char* src = (const char*)wp + (size_t)(p + 1) * 16384 +
                                  (size_t)seg * 1024 + (size_t)l * 16;
                __builtin_amdgcn_global_load_lds((const unsigned int*)src,
                    (unsigned int*)&Wb[ps ^ 1][seg * 512], 16, 0, 0);
            }
        }

        // th for chunk k0 (x rows stride 64 for k<32, hidden stride 68 after)
        const ushortT* th0p = (k0 < 32) ? (Xw + (size_t)k0 * 64)
                                        : (Xw + (size_t)(k0 - 32) * 68);
        __half2 th[2];
#pragma unroll
        for (int mt = 0; mt < 2; ++mt) {
            unsigned u = th0p[mt * 32 + l31];
            th[mt] = __builtin_bit_cast(__half2, (u << 16) | u);
        }

        // B-frags chunk k0: idx = nt*2+s
        f16x8 Bf[8];
#pragma unroll
        for (int nt = 0; nt < 4; ++nt)
#pragma unroll
            for (int s = 0; s < 2; ++s)
                Bf[nt * 2 + s] = *reinterpret_cast<const f16x8*>(
                    &Wb[ps][nt * 1024 + s * 512 + l * 8]);

        // Af chunk k0; then read th for k1 (th regs now free)
        AfU Af[2][2];
#pragma unroll
        for (int mt = 0; mt < 2; ++mt)
#pragma unroll
            for (int s = 0; s < 2; ++s)
#pragma unroll
                for (int q = 0; q < 4; ++q)
                    Af[mt][s].h2[q] = __hmul2(tf[mt][s][q], th[mt]);

        const ushortT* th1p = (k1 < 32) ? (Xw + (size_t)k1 * 64)
                                        : (Xw + (size_t)(k1 - 32) * 68);
#pragma unroll
        for (int mt = 0; mt < 2; ++mt) {
            unsigned u = th1p[mt * 32 + l31];
            th[mt] = __builtin_bit_cast(__half2, (u << 16) | u);
        }

        // burst 0: 16 MFMAs, s-OUTER (acc reuse distance = 8 MFMAs);
        // Bf[nt*2+s] reloaded for k1 right after its last chunk-k0 use
        __builtin_amdgcn_s_setprio(1);
#pragma unroll
        for (int s = 0; s < 2; ++s)
#pragma unroll
            for (int nt = 0; nt < 4; ++nt) {
#pragma unroll
                for (int mt = 0; mt < 2; ++mt)
                    acc[mt][nt] = __builtin_amdgcn_mfma_f32_32x32x16_f16(
                        Af[mt][s].v, Bf[nt * 2 + s], acc[mt][nt], 0, 0, 0);
                Bf[nt * 2 + s] = *reinterpret_cast<const f16x8*>(
                    &Wb[ps][4096 + nt * 1024 + s * 512 + l * 8]);
            }
        __builtin_amdgcn_s_setprio(0);

        // Af chunk k1 (th landed during burst 0)
#pragma unroll
        for (int mt = 0; mt < 2; ++mt)
#pragma unroll
            for (int s = 0; s < 2; ++s)
#pragma unroll
                for (int q = 0; q < 4; ++q)
                    Af[mt][s].h2[q] = __hmul2(tf[mt][s][q], th[mt]);

        // burst 1: s-OUTER again
        __builtin_amdgcn_s_setprio(1);
#pragma unroll
        for (int s = 0; s < 2; ++s)
#pragma unroll
            for (int nt = 0; nt < 4; ++nt)
#pragma unroll
                for (int mt = 0; mt < 2; ++mt)
                    acc[mt][nt] = __builtin_amdgcn_mfma_f32_32x32x16_f16(
                        Af[mt][s].v, Bf[nt * 2 + s], acc[mt][nt], 0, 0, 0);
        __builtin_amdgcn_s_setprio(0);

        __syncthreads();   // pair p+1 landed; all reads of slot ps done

        // layer boundary after phase 15 (chunks 30,31 complete layer 0)
        if (p == 15) {
            ushortT* Hw = Xw;   // union: x rows dead from here on
            // hidden channels o=0..63 (nt 0,1): store f16 at stride 68
#pragma unroll
            for (int nt = 0; nt < 2; ++nt) {
                float bn = b0[nt * 32 + l31];
                const int o = nt * 32 + l31;
#pragma unroll
                for (int mt = 0; mt < 2; ++mt)
#pragma unroll
                    for (int q = 0; q < 4; ++q) {
                        us4 hv;
#pragma unroll
                        for (int r = 0; r < 4; ++r) {
                            float y = fmaxf(acc[mt][nt][q * 4 + r] + bn, 0.f);
                            hv[r] = __builtin_bit_cast(ushortT, __float2half(y));
                        }
                        const int d = mt * 32 + q * 8 + g5 * 4;
                        *reinterpret_cast<us4*>(&Hw[o * 68 + d]) = hv;
                    }
            }
            // direct outputs o=64..127 (nt 2,3): sum over d
#pragma unroll
            for (int nt = 2; nt < 4; ++nt) {
                float bn = b0[nt * 32 + l31];
                float s = 0.f;
#pragma unroll
                for (int mt = 0; mt < 2; ++mt)
#pragma unroll
                    for (int r = 0; r < 16; ++r)
                        s += fmaxf(acc[mt][nt][r] + bn, 0.f);
                s += __shfl_xor(s, 32);
                if (l < 32) out[(size_t)b * 192 + (nt - 2) * 32 + l] = s;
            }
#pragma unroll
            for (int mt = 0; mt < 2; ++mt)
#pragma unroll
                for (int nt = 0; nt < 4; ++nt)
#pragma unroll
                    for (int r = 0; r < 16; ++r) acc[mt][nt][r] = 0.f;
        }
    }

    // layer-1 epilogue: all 4 nt-tiles are direct outputs
#pragma unroll
    for (int nt = 0; nt < 4; ++nt) {
        float bn = b1[nt * 32 + l31];
        float s = 0.f;
#pragma unroll
        for (int mt = 0; mt < 2; ++mt)
#pragma unroll
            for (int r = 0; r < 16; ++r)
                s += fmaxf(acc[mt][nt][r] + bn, 0.f);
        s += __shfl_xor(s, 32);
        if (l < 32) out[(size_t)b * 192 + 64 + nt * 32 + l] = s;
    }
}

// ---------- fp32 fallback, used only if ws too small ------
__global__ __launch_bounds__(256, 4) void cin_fp32_kernel(
    const float* __restrict__ x, const float* __restrict__ w0,
    const float* __restrict__ b0, const float* __restrict__ w1,
    const float* __restrict__ b1, float* __restrict__ out)
{
    const int b = blockIdx.x;
    const int tid = threadIdx.x;
    const int d = tid & 63;
    const int wave = tid >> 6;

    __shared__ float Xs[32][64];
    __shared__ float Hsf[64][64];

    const float* xb = x + (size_t)b * 2048;
    float treg[32];
#pragma unroll
    for (int f = 0; f < 32; ++f) treg[f] = xb[f * 64 + d];
    if (wave == 0) {
#pragma unroll
        for (int f = 0; f < 32; ++f) Xs[f][d] = treg[f];
    }
    __syncthreads();
    const int o_base = __builtin_amdgcn_readfirstlane(wave * 32);

    for (int oi = 0; oi < 32; ++oi) {
        const int o = o_base + oi;
        const float* wrow = w0 + (size_t)o * 1024;
        float acc = b0[o];
        for (int h = 0; h < 32; ++h) {
            const float* wv = wrow + h * 32;
            const float th = Xs[h][d];
            float s0 = 0.f, s1 = 0.f, s2 = 0.f, s3 = 0.f;
#pragma unroll
            for (int f = 0; f < 32; f += 4) {
                s0 = fmaf(wv[f + 0], treg[f + 0], s0);
                s1 = fmaf(wv[f + 1], treg[f + 1], s1);
                s2 = fmaf(wv[f + 2], treg[f + 2], s2);
                s3 = fmaf(wv[f + 3], treg[f + 3], s3);
            }
            acc = fmaf((s0 + s1) + (s2 + s3), th, acc);
        }
        float y = fmaxf(acc, 0.f);
        if (o < 64) {
            Hsf[o][d] = y;
        } else {
#pragma unroll
            for (int off = 32; off > 0; off >>= 1) y += __shfl_xor(y, off, 64);
            if (d == 0) out[(size_t)b * 192 + (o - 64)] = y;
        }
    }
    __syncthreads();

    for (int oi = 0; oi < 32; ++oi) {
        const int o = o_base + oi;
        const float* wrow = w1 + (size_t)o * 2048;
        float acc = b1[o];
        for (int h = 0; h < 64; ++h) {
            const float* wv = wrow + h * 32;
            const float th = Hsf[h][d];
            float s0 = 0.f, s1 = 0.f, s2 = 0.f, s3 = 0.f;
#pragma unroll
            for (int f = 0; f < 32; f += 4) {
                s0 = fmaf(wv[f + 0], treg[f + 0], s0);
                s1 = fmaf(wv[f + 1], treg[f + 1], s1);
                s2 = fmaf(wv[f + 2], treg[f + 2], s2);
                s3 = fmaf(wv[f + 3], treg[f + 3], s3);
            }
            acc = fmaf((s0 + s1) + (s2 + s3), th, acc);
        }
        float y = fmaxf(acc, 0.f);
#pragma unroll
        for (int off = 32; off > 0; off >>= 1) y += __shfl_xor(y, off, 64);
        if (d == 0) out[(size_t)b * 192 + 64 + o] = y;
    }
}

extern "C" void kernel_launch(void* const* d_in, const int* in_sizes, int n_in,
                              void* d_out, int out_size, void* d_ws, size_t ws_size,
                              hipStream_t stream) {
    const float* x  = (const float*)d_in[0];
    const float* w0 = (const float*)d_in[1];
    const float* b0 = (const float*)d_in[2];
    const float* w1 = (const float*)d_in[3];
    const float* b1 = (const float*)d_in[4];
    float* out = (float*)d_out;

    if (ws_size >= 786432) {
        ushortT* wp = (ushortT*)d_ws;
        cin_pack_w<<<192, 256, 0, stream>>>(w0, w1, wp);
        cin_mfma_kernel<<<1024, 256, 0, stream>>>(x, b0, b1, wp, out);
    } else {
        cin_fp32_kernel<<<4096, 256, 0, stream>>>(x, w0, b0, w1, b1, out);
    }
}

// Round 6
// 161.568 us; speedup vs baseline: 1.1301x; 1.1301x over previous
//
#include <hip/hip_runtime.h>
#include <hip/hip_fp16.h>

// CIN (xDeepFM), B=4096, F=32, D=64, layers 128/128.
// Per row m=(b,d): t = x[b,:,d] (32 f32)
//   layer0: y0[o] = relu(b0[o] + sum_{h,f} w0[o, h*32+f] t[h] t[f])
//   hidden = y0[0:64]; direct0 = y0[64:128]
//   layer1: y1[o] = relu(b1[o] + sum_{hh,f} w1[o, hh*32+f] hidden[hh] t[f])
//   out[b] = concat(direct0, y1) summed over d  -> (4096, 192) f32
//
// MFMA mapping (v_mfma_f32_16x16x32_f16):
//   A frag: lane holds A[m = l&15][k = (l>>4)*8 + j]
//   B frag: lane holds B[k = (l>>4)*8 + j][n = l&15]
//   C/D   : col = l&15, row = (l>>4)*4 + reg
//
// Round-15: R13/R14 (32x32x16) regressed ~20us twice with no counter
// explanation -> direction abandoned, reverted to R12's fat-phase
// 16x16x32 kernel (best: 162.5us). Two banked fixes on top:
// 1) hidden table stride 64 -> 68 ushorts: R12's boundary us4 writes at
//    stride-64 were a 16-way same-bank convoy (SQ_LDS_BANK_CONFLICT
//    4.19M ~= 2 phases of wall); stride 68 measured 0 conflicts in R13.
// 2) cross-barrier th prefetch: next phase's k0 th is read from the
//    WAVE-PRIVATE X/H table before the barrier (no slot hazard, unlike
//    Bf), removing the ~150cyc phase-start ds_read_u16 chain. At p==15
//    the prefetch is garbage (hidden not yet written) and is recomputed
//    inside the boundary block.

typedef __attribute__((ext_vector_type(8))) _Float16 f16x8;
typedef __attribute__((ext_vector_type(4))) float f32x4;
typedef __attribute__((ext_vector_type(4))) unsigned short us4;
typedef unsigned short ushortT;

// ---------- weight pre-pack: f32 -> f16 in B-fragment order ----------
// Stream chunk ktg (8192 B = 4096 ushorts): frag (ktg, n) at ushort
// offset ktg*4096 + n*512 + l*8.
// ktg<32 -> w0 kt=ktg; ktg>=32 -> w1 kt=ktg-32 (contiguous: 32*4096=131072).
__global__ void cin_pack_w(const float* __restrict__ w0,
                           const float* __restrict__ w1,
                           ushortT* __restrict__ wp) {
    int gidx = blockIdx.x * 256 + threadIdx.x;
    if (gidx >= 49152) return;
    const float* src;
    ushortT* dst;
    if (gidx < 16384) {
        int kk = gidx >> 9, rem = gidx & 511;
        int n = rem >> 6, lp = rem & 63;
        int o = n * 16 + (lp & 15);
        int c = kk * 32 + ((lp >> 4) << 3);
        src = w0 + o * 1024 + c;
        dst = wp + gidx * 8;
    } else {
        int g1 = gidx - 16384;
        int kk = g1 >> 9, rem = g1 & 511;
        int n = rem >> 6, lp = rem & 63;
        int o = n * 16 + (lp & 15);
        int c = kk * 32 + ((lp >> 4) << 3);
        src = w1 + o * 2048 + c;
        dst = wp + 131072 + g1 * 8;
    }
    ushortT tmp[8];
#pragma unroll
    for (int j = 0; j < 8; ++j) {
        __half h = __float2half(src[j]);
        tmp[j] = __builtin_bit_cast(ushortT, h);
    }
    *reinterpret_cast<f16x8*>(dst) = *reinterpret_cast<const f16x8*>(tmp);
}

__global__ __launch_bounds__(256, 2) void cin_mfma_kernel(
    const float* __restrict__ x,      // [4096][32][64]
    const float* __restrict__ b0,     // [128]
    const float* __restrict__ b1,     // [128]
    const ushortT* __restrict__ wp,   // packed weights (f16 bits)
    float* __restrict__ out)          // [4096][192]
{
    const int tid = threadIdx.x;
    const int l   = tid & 63;         // lane
    const int w   = tid >> 6;         // wave 0..3 -> b = blockIdx*4 + w
    const int b   = blockIdx.x * 4 + w;
    const int r16 = l & 15;
    const int g   = l >> 4;

    // Union buffer per wave: x table rows 0..31 (stride 64) during layer 0,
    // hidden rows 0..63 (stride 68, bank-friendly) after the boundary.
    __shared__ ushortT U[4][4352];                    // 34 KB
    __shared__ __align__(16) ushortT Wb[2][8192];     // pair dbuf (32 KB)

    ushortT* Xw = U[w];    // also the hidden table (stride 68) later

    // ---- prologue: x (f32) -> f16 table Xw rows 0..31 (own wave) ----
    const float* xb = x + (size_t)b * 2048;
#pragma unroll
    for (int i = 0; i < 8; ++i) {
        float4 v = reinterpret_cast<const float4*>(xb)[i * 64 + l];
        int flat = (i * 64 + l) * 4;
        us4 h;
        h[0] = __builtin_bit_cast(ushortT, __float2half(v.x));
        h[1] = __builtin_bit_cast(ushortT, __float2half(v.y));
        h[2] = __builtin_bit_cast(ushortT, __float2half(v.z));
        h[3] = __builtin_bit_cast(ushortT, __float2half(v.w));
        *reinterpret_cast<us4*>(&Xw[flat]) = h;
    }

    // ---- stage pair 0 (chunks 0,1 = 16 KB) into slot 0: 4 x 1 KB/wave ----
#pragma unroll
    for (int j = 0; j < 4; ++j) {
        const int seg = w * 4 + j;
        const char* src = (const char*)wp + (size_t)seg * 1024 + (size_t)l * 16;
        __builtin_amdgcn_global_load_lds((const unsigned int*)src,
                                         (unsigned int*)&Wb[0][seg * 512], 16, 0, 0);
    }
    __syncthreads();   // drains vmcnt (pair 0) + lgkm (Xw fill)

    // ---- base T-fragments: tf16[mt][p] = (t[d][g*8+2p], t[d][g*8+2p+1]) ----
    __half2 tf16[4][4];
#pragma unroll
    for (int mt = 0; mt < 4; ++mt)
#pragma unroll
        for (int p = 0; p < 4; ++p) {
            unsigned lo = Xw[(g * 8 + 2 * p) * 64 + mt * 16 + r16];
            unsigned hi = Xw[(g * 8 + 2 * p + 1) * 64 + mt * 16 + r16];
            tf16[mt][p] = __builtin_bit_cast(__half2, lo | (hi << 16));
        }

    f32x4 acc[4][8];
#pragma unroll
    for (int mt = 0; mt < 4; ++mt)
#pragma unroll
        for (int n = 0; n < 8; ++n) acc[mt][n] = (f32x4){0.f, 0.f, 0.f, 0.f};

    union AfU { __half2 h2[4]; f16x8 v; };

    // th for chunk 0, carried across phases in registers
    __half2 thc[4];
#pragma unroll
    for (int mt = 0; mt < 4; ++mt) {
        unsigned u = Xw[mt * 16 + r16];
        thc[mt] = __builtin_bit_cast(__half2, (u << 16) | u);
    }

    // ---------------- phase loop: 48 phases x 2 chunks ----------------
    // Phase p consumes pair p from slot p&1, stages pair p+1 into the
    // other slot. One barrier per phase (64 MFMAs per barrier). th for
    // the NEXT phase's k0 is prefetched before the barrier (wave-private
    // table, no hazard).
#pragma unroll 1
    for (int p = 0; p < 48; ++p) {
        const int ps = p & 1;
        const int k0 = 2 * p;
        const int k1 = k0 + 1;

        // stage next pair (issued first; lands during this phase body)
        if (p + 1 < 48) {
#pragma unroll
            for (int j = 0; j < 4; ++j) {
                const int seg = w * 4 + j;
                const char* src = (const char*)wp + (size_t)(p + 1) * 16384 +
                                  (size_t)seg * 1024 + (size_t)l * 16;
                __builtin_amdgcn_global_load_lds((const unsigned int*)src,
                    (unsigned int*)&Wb[ps ^ 1][seg * 512], 16, 0, 0);
            }
        }

        // B-frags for chunk k0
        f16x8 Bf[8];
#pragma unroll
        for (int n = 0; n < 8; ++n)
            Bf[n] = *reinterpret_cast<const f16x8*>(&Wb[ps][n * 512 + l * 8]);

        // Af for chunk k0 from carried thc (no LDS on this chain)
        AfU Af[4];
#pragma unroll
        for (int mt = 0; mt < 4; ++mt)
#pragma unroll
            for (int q = 0; q < 4; ++q)
                Af[mt].h2[q] = __hmul2(tf16[mt][q], thc[mt]);

        // th for chunk k1 (x rows stride 64, hidden rows stride 68)
        const ushortT* th1p = (k1 < 32) ? (Xw + (size_t)k1 * 64)
                                        : (Xw + (size_t)(k1 - 32) * 68);
        __half2 th1[4];
#pragma unroll
        for (int mt = 0; mt < 4; ++mt) {
            unsigned u = th1p[mt * 16 + r16];
            th1[mt] = __builtin_bit_cast(__half2, (u << 16) | u);
        }

        // burst 0; Bf[n] reloaded for chunk k1 right after last use
        __builtin_amdgcn_s_setprio(1);
#pragma unroll
        for (int n = 0; n < 8; ++n) {
#pragma unroll
            for (int mt = 0; mt < 4; ++mt)
                acc[mt][n] = __builtin_amdgcn_mfma_f32_16x16x32_f16(
                    Af[mt].v, Bf[n], acc[mt][n], 0, 0, 0);
            Bf[n] = *reinterpret_cast<const f16x8*>(&Wb[ps][4096 + n * 512 + l * 8]);
        }
        __builtin_amdgcn_s_setprio(0);

        // Af for chunk k1 (th1 landed during burst 0)
#pragma unroll
        for (int mt = 0; mt < 4; ++mt)
#pragma unroll
            for (int q = 0; q < 4; ++q)
                Af[mt].h2[q] = __hmul2(tf16[mt][q], th1[mt]);

        // burst 1
        __builtin_amdgcn_s_setprio(1);
#pragma unroll
        for (int n = 0; n < 8; ++n)
#pragma unroll
            for (int mt = 0; mt < 4; ++mt)
                acc[mt][n] = __builtin_amdgcn_mfma_f32_16x16x32_f16(
                    Af[mt].v, Bf[n], acc[mt][n], 0, 0, 0);
        __builtin_amdgcn_s_setprio(0);

        // prefetch th for next phase's k0 (wave-private table: hazard-free
        // across the barrier; p==15 value is garbage, recomputed below)
        if (p + 1 < 48) {
            const int k2 = k0 + 2;
            const ushortT* thp = (k2 < 32) ? (Xw + (size_t)k2 * 64)
                                           : (Xw + (size_t)(k2 - 32) * 68);
#pragma unroll
            for (int mt = 0; mt < 4; ++mt) {
                unsigned u = thp[mt * 16 + r16];
                thc[mt] = __builtin_bit_cast(__half2, (u << 16) | u);
            }
        }

        __syncthreads();   // pair p+1 landed; all reads of slot ps done

        // layer boundary after phase 15 (chunks 30,31 complete layer 0)
        if (p == 15) {
            ushortT* Hw = Xw;   // union: x rows dead from here on
            // hidden channels o=0..63 (n 0..3): f16 store at stride 68
#pragma unroll
            for (int n = 0; n < 4; ++n) {
                float bn = b0[n * 16 + r16];
                const int o = n * 16 + r16;
#pragma unroll
                for (int mt = 0; mt < 4; ++mt) {
                    us4 hv;
#pragma unroll
                    for (int r = 0; r < 4; ++r) {
                        float y = fmaxf(acc[mt][n][r] + bn, 0.f);
                        hv[r] = __builtin_bit_cast(ushortT, __float2half(y));
                    }
                    *reinterpret_cast<us4*>(&Hw[o * 68 + mt * 16 + g * 4]) = hv;
                }
            }
            // direct outputs o=64..127 (n 4..7): sum over d
#pragma unroll
            for (int n = 4; n < 8; ++n) {
                float bn = b0[n * 16 + r16];
                float s = 0.f;
#pragma unroll
                for (int mt = 0; mt < 4; ++mt)
#pragma unroll
                    for (int r = 0; r < 4; ++r)
                        s += fmaxf(acc[mt][n][r] + bn, 0.f);
                s += __shfl_xor(s, 16);
                s += __shfl_xor(s, 32);
                if (l < 16) out[(size_t)b * 192 + (n - 4) * 16 + l] = s;
            }
#pragma unroll
            for (int mt = 0; mt < 4; ++mt)
#pragma unroll
                for (int n = 0; n < 8; ++n) acc[mt][n] = (f32x4){0.f, 0.f, 0.f, 0.f};
            // th for chunk 32 = hidden row 0 (written just above, own wave)
#pragma unroll
            for (int mt = 0; mt < 4; ++mt) {
                unsigned u = Hw[mt * 16 + r16];
                thc[mt] = __builtin_bit_cast(__half2, (u << 16) | u);
            }
        }
    }

    // layer-1 epilogue: all 8 n-tiles are direct outputs
#pragma unroll
    for (int n = 0; n < 8; ++n) {
        float bn = b1[n * 16 + r16];
        float s = 0.f;
#pragma unroll
        for (int mt = 0; mt < 4; ++mt)
#pragma unroll
            for (int r = 0; r < 4; ++r)
                s += fmaxf(acc[mt][n][r] + bn, 0.f);
        s += __shfl_xor(s, 16);
        s += __shfl_xor(s, 32);
        if (l < 16) out[(size_t)b * 192 + 64 + n * 16 + l] = s;
    }
}

// ---------- fp32 fallback, used only if ws too small ------
__global__ __launch_bounds__(256, 4) void cin_fp32_kernel(
    const float* __restrict__ x, const float* __restrict__ w0,
    const float* __restrict__ b0, const float* __restrict__ w1,
    const float* __restrict__ b1, float* __restrict__ out)
{
    const int b = blockIdx.x;
    const int tid = threadIdx.x;
    const int d = tid & 63;
    const int wave = tid >> 6;

    __shared__ float Xs[32][64];
    __shared__ float Hsf[64][64];

    const float* xb = x + (size_t)b * 2048;
    float treg[32];
#pragma unroll
    for (int f = 0; f < 32; ++f) treg[f] = xb[f * 64 + d];
    if (wave == 0) {
#pragma unroll
        for (int f = 0; f < 32; ++f) Xs[f][d] = treg[f];
    }
    __syncthreads();
    const int o_base = __builtin_amdgcn_readfirstlane(wave * 32);

    for (int oi = 0; oi < 32; ++oi) {
        const int o = o_base + oi;
        const float* wrow = w0 + (size_t)o * 1024;
        float acc = b0[o];
        for (int h = 0; h < 32; ++h) {
            const float* wv = wrow + h * 32;
            const float th = Xs[h][d];
            float s0 = 0.f, s1 = 0.f, s2 = 0.f, s3 = 0.f;
#pragma unroll
            for (int f = 0; f < 32; f += 4) {
                s0 = fmaf(wv[f + 0], treg[f + 0], s0);
                s1 = fmaf(wv[f + 1], treg[f + 1], s1);
                s2 = fmaf(wv[f + 2], treg[f + 2], s2);
                s3 = fmaf(wv[f + 3], treg[f + 3], s3);
            }
            acc = fmaf((s0 + s1) + (s2 + s3), th, acc);
        }
        float y = fmaxf(acc, 0.f);
        if (o < 64) {
            Hsf[o][d] = y;
        } else {
#pragma unroll
            for (int off = 32; off > 0; off >>= 1) y += __shfl_xor(y, off, 64);
            if (d == 0) out[(size_t)b * 192 + (o - 64)] = y;
        }
    }
    __syncthreads();

    for (int oi = 0; oi < 32; ++oi) {
        const int o = o_base + oi;
        const float* wrow = w1 + (size_t)o * 2048;
        float acc = b1[o];
        for (int h = 0; h < 64; ++h) {
            const float* wv = wrow + h * 32;
            const float th = Hsf[h][d];
            float s0 = 0.f, s1 = 0.f, s2 = 0.f, s3 = 0.f;
#pragma unroll
            for (int f = 0; f < 32; f += 4) {
                s0 = fmaf(wv[f + 0], treg[f + 0], s0);
                s1 = fmaf(wv[f + 1], treg[f + 1], s1);
                s2 = fmaf(wv[f + 2], treg[f + 2], s2);
                s3 = fmaf(wv[f + 3], treg[f + 3], s3);
            }
            acc = fmaf((s0 + s1) + (s2 + s3), th, acc);
        }
        float y = fmaxf(acc, 0.f);
#pragma unroll
        for (int off = 32; off > 0; off >>= 1) y += __shfl_xor(y, off, 64);
        if (d == 0) out[(size_t)b * 192 + 64 + o] = y;
    }
}

extern "C" void kernel_launch(void* const* d_in, const int* in_sizes, int n_in,
                              void* d_out, int out_size, void* d_ws, size_t ws_size,
                              hipStream_t stream) {
    const float* x  = (const float*)d_in[0];
    const float* w0 = (const float*)d_in[1];
    const float* b0 = (const float*)d_in[2];
    const float* w1 = (const float*)d_in[3];
    const float* b1 = (const float*)d_in[4];
    float* out = (float*)d_out;

    if (ws_size >= 786432) {
        ushortT* wp = (ushortT*)d_ws;
        cin_pack_w<<<192, 256, 0, stream>>>(w0, w1, wp);
        cin_mfma_kernel<<<1024, 256, 0, stream>>>(x, b0, b1, wp, out);
    } else {
        cin_fp32_kernel<<<4096, 256, 0, stream>>>(x, w0, b0, w1, b1, out);
    }
}